// Round 15
// baseline (432.211 us; speedup 1.0000x reference)
//
#include <hip/hip_runtime.h>
#include <stdint.h>

// ---------------------------------------------------------------------------
// HeteroGraphSAGE encoder, MI355X round 15.
// Round-14: 390us, agg4 (92+77us) dominant at its byte count. Last byte cut:
// fuse the USER mean (205MB gather + 51MB write + 51MB read per layer) into
// the user update kernel: 16-lane cooperative groups gather 64 rows' means
// into swizzled LDS (overlapped with async W staging), then r12 tile core
// with addv from LDS. Movie/tag segments remain in agg4 (3 segs L0, 2 L1).
// Everything else identical to round 14.
// ---------------------------------------------------------------------------

#define NUSR 200000
#define NMOV 50000
#define NTAG 20000
#define FDIM 64
#define HDIM 128
#define NE1  800000
#define NE2  400000

#define OFF_RM 0
#define OFF_RU (NMOV)
#define OFF_TM (NMOV + NUSR)
#define OFF_TT (NMOV + NUSR + NMOV)
#define NTOT   (2 * NMOV + NUSR + NTAG)      // 320000
#define ETOT   (2 * NE1 + 2 * NE2)           // 2.4M
#define WHH    (HDIM * HDIM)

// replicated weight block (PRE-SWIZZLED rows): [0,8192) movie_W; per layer l:
// 8192 + l*7*WHH + e*WHH, e: 0..3 Wn[l,e]; 4 Ws[l,1]; 5 Ws[l,2]; 6 Ws[l,0]+Ws[l,3].
#define WTOT (8192 + 2 * 7 * WHH)
#define BREP 768
// bias replica layout: [0)movie_b [128)b_l0_user [256)b_l0_tag
//                      [384)bcc_l0 [512)b_l1_user [640)bcc_l1

#define NB0 196
#define NB1 196
#define NB2 98
#define NB3 157
#define NB  (NB0 + NB1 + NB2 + NB3)          // 647
#define S1_EPB 8192
#define S1_B0 98
#define S1_B1 98
#define S1_B2 49
#define S1_B3 49
#define S1_NBLK (S1_B0 + S1_B1 + S1_B2 + S1_B3)  // 294
#define CAP 6144

typedef short bf16x8 __attribute__((ext_vector_type(8)));
typedef float f32x4 __attribute__((ext_vector_type(4)));

static inline int cdiv(int a, int b) { return (a + b - 1) / b; }

__device__ __forceinline__ float bf2f(unsigned short u) {
    union { unsigned int i; float f; } c;
    c.i = ((unsigned int)u) << 16;
    return c.f;
}
__device__ __forceinline__ unsigned short f2bf(float f) {
    union { float f; unsigned int i; } c;
    c.f = f;
    unsigned int i = c.i;
    return (unsigned short)((i + 0x7fffu + ((i >> 16) & 1u)) >> 16);  // RNE
}

// async global->LDS, 16 bytes per lane (linear LDS dest = wave base + lane*16)
__device__ __forceinline__ void gload_lds16(const unsigned short* g, unsigned short* l) {
    __builtin_amdgcn_global_load_lds(
        (const __attribute__((address_space(1))) unsigned int*)(g),
        (__attribute__((address_space(3))) unsigned int*)(l), 16, 0, 0);
}

// ---------------------------------------------------------------------------
// CSR build pieces (round-4 bucketized design)
// ---------------------------------------------------------------------------
struct SegInfo {
    int e0, eN, sh, sbb, nb;
    const int* dstA;
    const int* srcA;
};
__device__ __forceinline__ SegInfo seg_decode(int blk, const int* ru, const int* rm,
                                              const int* tm, const int* tt) {
    SegInfo s;
    if (blk < S1_B0) {
        s.e0 = blk * S1_EPB; s.eN = NE1; s.sh = 8;  s.sbb = 0;                 s.nb = NB0;
        s.dstA = rm; s.srcA = ru;
    } else if (blk < S1_B0 + S1_B1) {
        s.e0 = (blk - S1_B0) * S1_EPB; s.eN = NE1; s.sh = 10; s.sbb = NB0;     s.nb = NB1;
        s.dstA = ru; s.srcA = rm;
    } else if (blk < S1_B0 + S1_B1 + S1_B2) {
        s.e0 = (blk - S1_B0 - S1_B1) * S1_EPB; s.eN = NE2; s.sh = 9;
        s.sbb = NB0 + NB1; s.nb = NB2;
        s.dstA = tm; s.srcA = tt;
    } else {
        s.e0 = (blk - S1_B0 - S1_B1 - S1_B2) * S1_EPB; s.eN = NE2; s.sh = 7;
        s.sbb = NB0 + NB1 + NB2; s.nb = NB3;
        s.dstA = tt; s.srcA = tm;
    }
    return s;
}

__global__ __launch_bounds__(256) void csr_bin(const int* __restrict__ ru,
                                               const int* __restrict__ rm,
                                               const int* __restrict__ tm,
                                               const int* __restrict__ tt,
                                               int* __restrict__ bcur,
                                               int* __restrict__ tmp) {
    __shared__ int h[256], st[256], gb[256], cu[256];
    __shared__ int rec[S1_EPB];
    __shared__ unsigned short bk[S1_EPB];
    const int t = threadIdx.x;
    h[t] = 0;
    __syncthreads();
    const SegInfo s = seg_decode(blockIdx.x, ru, rm, tm, tt);
    const int mask = (1 << s.sh) - 1;
#pragma unroll 4
    for (int i = 0; i < S1_EPB / 256; ++i) {
        const int e = s.e0 + t + i * 256;
        if (e < s.eN) atomicAdd(&h[s.dstA[e] >> s.sh], 1);
    }
    __syncthreads();
    const int v = h[t];
    cu[t] = v;
    __syncthreads();
    for (int off = 1; off < 256; off <<= 1) {
        const int add = (t >= off) ? cu[t - off] : 0;
        __syncthreads();
        cu[t] += add;
        __syncthreads();
    }
    st[t] = cu[t] - v;
    gb[t] = (t < s.nb && v) ? atomicAdd(&bcur[s.sbb + t], v) : 0;
    cu[t] = st[t];
    __syncthreads();
#pragma unroll 4
    for (int i = 0; i < S1_EPB / 256; ++i) {
        const int e = s.e0 + t + i * 256;
        if (e < s.eN) {
            const int d = s.dstA[e];
            const int lb = d >> s.sh;
            const int r = ((d & mask) << 18) | s.srcA[e];
            const int p = atomicAdd(&cu[lb], 1);
            rec[p] = r;
            bk[p] = (unsigned short)lb;
        }
    }
    __syncthreads();
    const int ecount = min(S1_EPB, s.eN - s.e0);
    for (int q = t; q < ecount; q += 256) {
        const int lb = bk[q];
        tmp[gb[lb] + (q - st[lb])] = rec[q];
    }
}

__global__ __launch_bounds__(256) void csr_sort(const int* __restrict__ tmp,
                                                const int* __restrict__ bbase,
                                                int* __restrict__ rowptr,
                                                int* __restrict__ sorted) {
    __shared__ int h[1024];
    __shared__ int part[256];
    __shared__ int outb[CAP];
    const int b = blockIdx.x;
    const int t = threadIdx.x;
    int c0, nctr;
    if (b < NB0)                 { c0 = OFF_RM + (b << 8);                nctr = min(256,  NMOV - (b << 8)); }
    else if (b < NB0 + NB1)      { const int j = b - NB0;                 c0 = OFF_RU + (j << 10); nctr = min(1024, NUSR - (j << 10)); }
    else if (b < NB0 + NB1 + NB2){ const int j = b - NB0 - NB1;           c0 = OFF_TM + (j << 9);  nctr = min(512,  NMOV - (j << 9)); }
    else                         { const int j = b - NB0 - NB1 - NB2;     c0 = OFF_TT + (j << 7);  nctr = min(128,  NTAG - (j << 7)); }
    for (int k = t; k < 1024; k += 256) h[k] = 0;
    __syncthreads();
    const int lo = bbase[b], hi = bbase[b + 1];
    const int n = hi - lo;
    for (int e = lo + t; e < hi; e += 256) atomicAdd(&h[tmp[e] >> 18], 1);
    __syncthreads();
    const int b4 = t * 4;
    const int a0 = h[b4], a1 = h[b4 + 1], a2 = h[b4 + 2], a3 = h[b4 + 3];
    const int sum = a0 + a1 + a2 + a3;
    part[t] = sum;
    __syncthreads();
    for (int off = 1; off < 256; off <<= 1) {
        const int add = (t >= off) ? part[t - off] : 0;
        __syncthreads();
        part[t] += add;
        __syncthreads();
    }
    int run = part[t] - sum;
    h[b4] = run; run += a0;
    h[b4 + 1] = run; run += a1;
    h[b4 + 2] = run; run += a2;
    h[b4 + 3] = run;
    __syncthreads();
    for (int k = t; k < nctr; k += 256) rowptr[c0 + k] = lo + h[k];
    __syncthreads();
    if (n <= CAP) {
        for (int e = lo + t; e < hi; e += 256) {
            const int r = tmp[e];
            const int p = atomicAdd(&h[r >> 18], 1);
            outb[p] = r & 0x3FFFF;
        }
        __syncthreads();
        for (int q = t; q < n; q += 256) sorted[lo + q] = outb[q];
    } else {
        for (int e = lo + t; e < hi; e += 256) {
            const int r = tmp[e];
            const int p = atomicAdd(&h[r >> 18], 1);
            sorted[lo + p] = r & 0x3FFFF;
        }
    }
}

// ---------------------------------------------------------------------------
// merged prep: f32->bf16 converts + 8-replica SWIZZLED weight pack + biases
// + zero bcnt.
// ---------------------------------------------------------------------------
__global__ __launch_bounds__(256) void prep_all(
    const float* __restrict__ i0, unsigned short* __restrict__ o0, int n0,
    const float* __restrict__ i1, unsigned short* __restrict__ o1, int n1,
    const float* __restrict__ i2, unsigned short* __restrict__ o2, int n2,
    int gcvt,
    const float* __restrict__ movie_W, const float* __restrict__ movie_b,
    const float* __restrict__ Wn, const float* __restrict__ Ws,
    const float* __restrict__ bs,
    unsigned short* __restrict__ WB, float* __restrict__ BB,
    int* __restrict__ bcnt) {
    if ((int)blockIdx.x < gcvt) {
        int i = blockIdx.x * 256 + threadIdx.x;
        const float* in; unsigned short* out;
        if (i < n0) { in = i0; out = o0; }
        else if (i < n0 + n1) { in = i1; out = o1; i -= n0; }
        else if (i < n0 + n1 + n2) { in = i2; out = o2; i -= n0 + n1; }
        else return;
        const float4 v = ((const float4*)in)[i];
        ushort4 o;
        o.x = f2bf(v.x); o.y = f2bf(v.y); o.z = f2bf(v.z); o.w = f2bf(v.w);
        ((ushort4*)out)[i] = o;
        return;
    }
    const int i = (blockIdx.x - gcvt) * 256 + threadIdx.x;
    if (i <= NB) bcnt[i] = 0;
    if (i < BREP) {
        const int seg = i >> 7, c = i & 127;
        float bv;
        if (seg == 0)      bv = movie_b[c];
        else if (seg == 1) bv = bs[0 * 512 + 1 * 128 + c];
        else if (seg == 2) bv = bs[0 * 512 + 2 * 128 + c];
        else if (seg == 3) bv = bs[0 * 512 + 0 * 128 + c] + bs[0 * 512 + 3 * 128 + c];
        else if (seg == 4) bv = bs[1 * 512 + 1 * 128 + c];
        else               bv = bs[1 * 512 + 0 * 128 + c] + bs[1 * 512 + 3 * 128 + c];
#pragma unroll
        for (int r = 0; r < 8; ++r) BB[r * BREP + i] = bv;
    }
    if (i < WTOT) {
        float v;
        int dest;
        if (i < 8192) {
            v = movie_W[i];
            const int r0 = i >> 6, c0 = i & 63;
            dest = (r0 << 6) + ((((c0 >> 3) ^ (r0 & 7)) << 3) | (c0 & 7));
        } else {
            const int j = i - 8192;
            const int l = j / (7 * WHH);
            const int rr = j % (7 * WHH);
            const int e = rr / WHH;
            const int o = rr % WHH;
            if (e < 4) v = Wn[(l * 4 + e) * WHH + o];
            else if (e == 4) v = Ws[(l * 4 + 1) * WHH + o];
            else if (e == 5) v = Ws[(l * 4 + 2) * WHH + o];
            else v = Ws[(l * 4 + 0) * WHH + o] + Ws[(l * 4 + 3) * WHH + o];
            const int r0 = o >> 7, c0 = o & 127;
            dest = 8192 + l * 7 * WHH + e * WHH +
                   (r0 << 7) + ((((c0 >> 3) ^ (r0 & 7)) << 3) | (c0 & 7));
        }
        const unsigned short bf = f2bf(v);
#pragma unroll
        for (int r = 0; r < 8; ++r) WB[(size_t)r * WTOT + dest] = bf;
    }
}

// ---------------------------------------------------------------------------
// merged mean aggregation (round-12 proven): 16-lane groups, 2-deep unroll.
// Now used for movie/tag segments only.
// ---------------------------------------------------------------------------
__global__ __launch_bounds__(256) void agg4(
    const unsigned short* __restrict__ f0, const int* __restrict__ rp0, unsigned short* __restrict__ o0,
    const unsigned short* __restrict__ f1, const int* __restrict__ rp1, unsigned short* __restrict__ o1,
    const unsigned short* __restrict__ f2, const int* __restrict__ rp2, unsigned short* __restrict__ o2,
    const unsigned short* __restrict__ f3, const int* __restrict__ rp3, unsigned short* __restrict__ o3,
    int c0, int c1, int c2, int c3,
    const int* __restrict__ sorted) {
    int g = blockIdx.x * 16 + (threadIdx.x >> 4);
    const unsigned short* feat; const int* rp; unsigned short* out;
    if (g < c0) { feat = f0; rp = rp0; out = o0; }
    else if (g < c1) { feat = f1; rp = rp1; out = o1; g -= c0; }
    else if (g < c2) { feat = f2; rp = rp2; out = o2; g -= c1; }
    else if (g < c3) { feat = f3; rp = rp3; out = o3; g -= c2; }
    else return;
    const int lane = threadIdx.x & 15;
    const int s = rp[g], e = rp[g + 1];
    float a[8];
#pragma unroll
    for (int k = 0; k < 8; ++k) a[k] = 0.f;
    int j = s;
    for (; j + 1 < e; j += 2) {
        const int s0 = sorted[j], s1 = sorted[j + 1];
        const bf16x8 v0 = *(const bf16x8*)&feat[(size_t)s0 * HDIM + lane * 8];
        const bf16x8 v1 = *(const bf16x8*)&feat[(size_t)s1 * HDIM + lane * 8];
#pragma unroll
        for (int k = 0; k < 8; ++k) a[k] += bf2f((unsigned short)v0[k]) + bf2f((unsigned short)v1[k]);
    }
    if (j < e) {
        const int s0 = sorted[j];
        const bf16x8 v0 = *(const bf16x8*)&feat[(size_t)s0 * HDIM + lane * 8];
#pragma unroll
        for (int k = 0; k < 8; ++k) a[k] += bf2f((unsigned short)v0[k]);
    }
    const float sc = (e > s) ? 1.0f / (float)(e - s) : 0.0f;
    bf16x8 o;
#pragma unroll
    for (int k = 0; k < 8; ++k) o[k] = (short)f2bf(a[k] * sc);
    *(bf16x8*)&out[(size_t)g * HDIM + lane * 8] = o;
}

// ---------------------------------------------------------------------------
// GEMM tile core (round-12, verified): one 64x128 tile per 256-thr block;
// W staged into LDS via global_load_lds (source rows pre-swizzled).
// ---------------------------------------------------------------------------
template <int K, bool TWO, bool HAS_ADD, bool HAS_BIAS, bool LEAKY, bool OUT_F32>
__device__ __forceinline__ void tile_core_lds(
    unsigned short* wlds,
    const unsigned short* __restrict__ X1, const unsigned short* __restrict__ W1s,
    const unsigned short* __restrict__ X2, const unsigned short* __restrict__ W2s,
    const unsigned short* __restrict__ addv, const float* __restrict__ bias,
    void* __restrict__ out, int n, int blk) {
    constexpr int NC = K / 32;
    constexpr int PASSES = (128 * K) / 2048;   // 2048 elems staged per pass
    const int t = threadIdx.x;
    const int lane = t & 63;
    const int wv = t >> 6;
    const int fr = lane & 15, fq = lane >> 4;
    const int swz = fr & 7;
    const int r = blk * 64 + wv * 16 + fr;
    const int rc = (r < n) ? r : (n - 1);

#pragma unroll
    for (int p = 0; p < PASSES; ++p)
        gload_lds16(W1s + (p * 256 + t) * 8, wlds + (p * 256 + t) * 8);

    bf16x8 xf[NC];
    {
        const unsigned short* xp = X1 + (size_t)rc * K + fq * 8;
#pragma unroll
        for (int c = 0; c < NC; ++c) xf[c] = *(const bf16x8*)(xp + c * 32);
    }

    f32x4 acc[8];
#pragma unroll
    for (int nn = 0; nn < 8; ++nn) acc[nn] = (f32x4){0.f, 0.f, 0.f, 0.f};

    __syncthreads();

#pragma unroll
    for (int nn = 0; nn < 8; ++nn) {
        const int rowoff = (nn * 16 + fr) * K;
#pragma unroll
        for (int c = 0; c < NC; ++c) {
            const bf16x8 wf = *(const bf16x8*)&wlds[rowoff + (((fq + 4 * c) ^ swz) << 3)];
            acc[nn] = __builtin_amdgcn_mfma_f32_16x16x32_bf16(wf, xf[c], acc[nn], 0, 0, 0);
        }
    }

    if (TWO) {
        __syncthreads();
#pragma unroll
        for (int p = 0; p < PASSES; ++p)
            gload_lds16(W2s + (p * 256 + t) * 8, wlds + (p * 256 + t) * 8);
        {
            const unsigned short* xp = X2 + (size_t)rc * K + fq * 8;
#pragma unroll
            for (int c = 0; c < NC; ++c) xf[c] = *(const bf16x8*)(xp + c * 32);
        }
        __syncthreads();
#pragma unroll
        for (int nn = 0; nn < 8; ++nn) {
            const int rowoff = (nn * 16 + fr) * K;
#pragma unroll
            for (int c = 0; c < NC; ++c) {
                const bf16x8 wf = *(const bf16x8*)&wlds[rowoff + (((fq + 4 * c) ^ swz) << 3)];
                acc[nn] = __builtin_amdgcn_mfma_f32_16x16x32_bf16(wf, xf[c], acc[nn], 0, 0, 0);
            }
        }
    }

    if (r < n) {
#pragma unroll
        for (int nn = 0; nn < 8; ++nn) {
            const int c0 = nn * 16 + fq * 4;
            float v0 = acc[nn][0], v1 = acc[nn][1], v2 = acc[nn][2], v3 = acc[nn][3];
            if (HAS_BIAS) {
                const float4 bv = *(const float4*)&bias[c0];
                v0 += bv.x; v1 += bv.y; v2 += bv.z; v3 += bv.w;
            }
            if (HAS_ADD) {
                const ushort4 ad = *(const ushort4*)&addv[(size_t)r * HDIM + c0];
                v0 += bf2f(ad.x); v1 += bf2f(ad.y); v2 += bf2f(ad.z); v3 += bf2f(ad.w);
            }
            if (LEAKY) {
                v0 = v0 > 0.f ? v0 : 0.1f * v0;
                v1 = v1 > 0.f ? v1 : 0.1f * v1;
                v2 = v2 > 0.f ? v2 : 0.1f * v2;
                v3 = v3 > 0.f ? v3 : 0.1f * v3;
            }
            if (OUT_F32) {
                float4 o; o.x = v0; o.y = v1; o.z = v2; o.w = v3;
                *(float4*)&((float*)out)[(size_t)r * HDIM + c0] = o;
            } else {
                ushort4 o;
                o.x = f2bf(v0); o.y = f2bf(v1); o.z = f2bf(v2); o.w = f2bf(v3);
                *(ushort4*)&((unsigned short*)out)[(size_t)r * HDIM + c0] = o;
            }
        }
    }
}

// ---------------------------------------------------------------------------
// fused user update: per block, gather 64 rows' addv means into swizzled LDS
// (16-lane groups, 4 rows each — agg4's uniform-control structure), then the
// r12 tile core with addv from LDS. out = leaky(X@Ws^T + b + mean(GT)).
// LDS: wlds 32KB + alds 16KB = 48KB -> 3 blocks/CU.
// ---------------------------------------------------------------------------
template <bool OUT_F32>
__global__ __launch_bounds__(256, 3) void fused_user(
    const unsigned short* __restrict__ X,
    const unsigned short* __restrict__ GT,
    const int* __restrict__ rp, const int* __restrict__ sorted,
    const unsigned short* __restrict__ WB, int woff,
    const float* __restrict__ BB, int boff,
    void* __restrict__ out, int n) {
    __shared__ __align__(16) unsigned short wlds[128 * HDIM];   // 32 KB
    __shared__ __align__(16) unsigned short alds[64 * HDIM];    // 16 KB
    const int t = threadIdx.x;
    const int lane = t & 63;
    const int wv = t >> 6;
    const int fr = lane & 15, fq = lane >> 4;
    const int swz = fr & 7;
    const int rep = blockIdx.x & 7;
    const unsigned short* Ws = WB + (size_t)rep * WTOT + woff;
    const float* bias = BB + rep * BREP + boff;
    const int r = blockIdx.x * 64 + wv * 16 + fr;
    const int rc = (r < n) ? r : (n - 1);

    // kick off async W staging first
#pragma unroll
    for (int p = 0; p < 8; ++p)
        gload_lds16(Ws + (p * 256 + t) * 8, wlds + (p * 256 + t) * 8);

    // phase A: gather means for this block's 64 rows (group = 4 rows)
    {
        const int grp = t >> 4;
        const int l16 = t & 15;
#pragma unroll 1
        for (int rr = 0; rr < 4; ++rr) {
            const int row_loc = grp * 4 + rr;
            int grow = blockIdx.x * 64 + row_loc;
            if (grow >= n) grow = n - 1;
            const int s = rp[grow], e = rp[grow + 1];
            float a[8];
#pragma unroll
            for (int k = 0; k < 8; ++k) a[k] = 0.f;
            int j = s;
            for (; j + 1 < e; j += 2) {
                const int s0 = sorted[j], s1 = sorted[j + 1];
                const bf16x8 v0 = *(const bf16x8*)&GT[(size_t)s0 * HDIM + l16 * 8];
                const bf16x8 v1 = *(const bf16x8*)&GT[(size_t)s1 * HDIM + l16 * 8];
#pragma unroll
                for (int k = 0; k < 8; ++k)
                    a[k] += bf2f((unsigned short)v0[k]) + bf2f((unsigned short)v1[k]);
            }
            if (j < e) {
                const int s0 = sorted[j];
                const bf16x8 v0 = *(const bf16x8*)&GT[(size_t)s0 * HDIM + l16 * 8];
#pragma unroll
                for (int k = 0; k < 8; ++k) a[k] += bf2f((unsigned short)v0[k]);
            }
            const float sc = (e > s) ? 1.0f / (float)(e - s) : 0.0f;
            bf16x8 o;
#pragma unroll
            for (int k = 0; k < 8; ++k) o[k] = (short)f2bf(a[k] * sc);
            // chunk-xor swizzle (same involution as W layout)
            *(bf16x8*)&alds[row_loc * HDIM + ((l16 ^ (row_loc & 7)) << 3)] = o;
        }
    }

    // X fragments
    bf16x8 xf[4];
    {
        const unsigned short* xp = X + (size_t)rc * HDIM + fq * 8;
#pragma unroll
        for (int c = 0; c < 4; ++c) xf[c] = *(const bf16x8*)(xp + c * 32);
    }

    f32x4 acc[8];
#pragma unroll
    for (int nn = 0; nn < 8; ++nn) acc[nn] = (f32x4){0.f, 0.f, 0.f, 0.f};

    __syncthreads();   // drains gather ds_writes (lgkm) + W staging (vmcnt)

#pragma unroll
    for (int nn = 0; nn < 8; ++nn) {
        const int rowoff = (nn * 16 + fr) * HDIM;
#pragma unroll
        for (int c = 0; c < 4; ++c) {
            const bf16x8 wf = *(const bf16x8*)&wlds[rowoff + (((fq + 4 * c) ^ swz) << 3)];
            acc[nn] = __builtin_amdgcn_mfma_f32_16x16x32_bf16(wf, xf[c], acc[nn], 0, 0, 0);
        }
    }

    if (r < n) {
        const int row_loc = wv * 16 + fr;
#pragma unroll
        for (int nn = 0; nn < 8; ++nn) {
            const int c0 = nn * 16 + fq * 4;
            const int ci = c0 >> 3;                       // 16B chunk index
            const ushort4 ad = *(const ushort4*)&alds[row_loc * HDIM +
                                                      ((ci ^ (row_loc & 7)) << 3) + (c0 & 7)];
            const float4 bv = *(const float4*)&bias[c0];
            float v0 = acc[nn][0] + bv.x + bf2f(ad.x);
            float v1 = acc[nn][1] + bv.y + bf2f(ad.y);
            float v2 = acc[nn][2] + bv.z + bf2f(ad.z);
            float v3 = acc[nn][3] + bv.w + bf2f(ad.w);
            v0 = v0 > 0.f ? v0 : 0.1f * v0;
            v1 = v1 > 0.f ? v1 : 0.1f * v1;
            v2 = v2 > 0.f ? v2 : 0.1f * v2;
            v3 = v3 > 0.f ? v3 : 0.1f * v3;
            if (OUT_F32) {
                float4 o; o.x = v0; o.y = v1; o.z = v2; o.w = v3;
                *(float4*)&((float*)out)[(size_t)r * HDIM + c0] = o;
            } else {
                ushort4 o;
                o.x = f2bf(v0); o.y = f2bf(v1); o.z = f2bf(v2); o.w = f2bf(v3);
                *(ushort4*)&((unsigned short*)out)[(size_t)r * HDIM + c0] = o;
            }
        }
    }
}

// ---------------------------------------------------------------------------
// merged: CSR bucket-hist (blocks [0,nhist)) + genre GEMM (rest).
// ---------------------------------------------------------------------------
__global__ __launch_bounds__(256, 5) void hist_genre(
    const int* __restrict__ ru, const int* __restrict__ rm,
    const int* __restrict__ tm, const int* __restrict__ tt,
    int* __restrict__ bcnt, int nhist,
    const unsigned short* __restrict__ X, const unsigned short* __restrict__ WB,
    const float* __restrict__ BB, unsigned short* __restrict__ out, int n) {
    __shared__ __align__(16) unsigned short wlds[128 * FDIM];
    const int b = blockIdx.x;
    if (b < nhist) {
        int* h = (int*)wlds;
        const int t = threadIdx.x;
        h[t] = 0;
        __syncthreads();
        const SegInfo s = seg_decode(b, ru, rm, tm, tt);
#pragma unroll 4
        for (int i = 0; i < S1_EPB / 256; ++i) {
            const int e = s.e0 + t + i * 256;
            if (e < s.eN) atomicAdd(&h[s.dstA[e] >> s.sh], 1);
        }
        __syncthreads();
        if (t < s.nb) {
            const int c = h[t];
            if (c) atomicAdd(&bcnt[s.sbb + t], c);
        }
        return;
    }
    const int gb = b - nhist;
    const int rep = gb & 7;
    tile_core_lds<FDIM, false, false, true, false, false>(
        wlds, X, WB + (size_t)rep * WTOT, nullptr, nullptr, nullptr,
        BB + rep * BREP, out, n, gb);
}

// ---------------------------------------------------------------------------
// merged: bucket-scan (block 0) + layer-0 pre-transform GEMMs.
// ---------------------------------------------------------------------------
__global__ __launch_bounds__(256, 5) void bscan_pre2(
    const int* __restrict__ bcnt, int* __restrict__ bbase, int* __restrict__ bcur,
    int* __restrict__ rowptr,
    const unsigned short* __restrict__ Xa, unsigned short* __restrict__ oa, int na, int nba,
    const unsigned short* __restrict__ Xb, unsigned short* __restrict__ ob, int nb_,
    const unsigned short* __restrict__ WB, int offA, int offB) {
    __shared__ __align__(16) unsigned short wlds[128 * HDIM];
    const int b = blockIdx.x;
    if (b == 0) {
        int* sh = (int*)wlds;
        const int t = threadIdx.x;
        int v[3];
        int s = 0;
#pragma unroll
        for (int k = 0; k < 3; ++k) {
            const int idx = t * 3 + k;
            v[k] = (idx < NB) ? bcnt[idx] : 0;
            s += v[k];
        }
        sh[t] = s;
        __syncthreads();
        for (int off = 1; off < 256; off <<= 1) {
            const int add = (t >= off) ? sh[t - off] : 0;
            __syncthreads();
            sh[t] += add;
            __syncthreads();
        }
        int run = sh[t] - s;
#pragma unroll
        for (int k = 0; k < 3; ++k) {
            const int idx = t * 3 + k;
            if (idx < NB) { bbase[idx] = run; bcur[idx] = run; }
            run += v[k];
        }
        if (t == 255) bbase[NB] = run;
        if (t == 0) rowptr[NTOT] = ETOT;
        return;
    }
    const int pb = b - 1;
    const int rep = pb & 7;
    const unsigned short* WR = WB + (size_t)rep * WTOT;
    if (pb < nba)
        tile_core_lds<HDIM, false, false, false, false, false>(
            wlds, Xa, WR + offA, nullptr, nullptr, nullptr, nullptr, oa, na, pb);
    else
        tile_core_lds<HDIM, false, false, false, false, false>(
            wlds, Xb, WR + offB, nullptr, nullptr, nullptr, nullptr, ob, nb_, pb - nba);
}

// plain pre2 (layer 1)
__global__ __launch_bounds__(256, 5) void gemm_pre2(
    const unsigned short* __restrict__ Xa, unsigned short* __restrict__ oa, int na, int nba,
    const unsigned short* __restrict__ Xb, unsigned short* __restrict__ ob, int nb_,
    const unsigned short* __restrict__ WB, int offA, int offB) {
    __shared__ __align__(16) unsigned short wlds[128 * HDIM];
    const int b = blockIdx.x;
    const int rep = b & 7;
    const unsigned short* WR = WB + (size_t)rep * WTOT;
    if (b < nba)
        tile_core_lds<HDIM, false, false, false, false, false>(
            wlds, Xa, WR + offA, nullptr, nullptr, nullptr, nullptr, oa, na, b);
    else
        tile_core_lds<HDIM, false, false, false, false, false>(
            wlds, Xb, WR + offB, nullptr, nullptr, nullptr, nullptr, ob, nb_, b - nba);
}

// layer-0 update, movie + tag only (user is fused)
__global__ __launch_bounds__(256, 5) void upd_l0(
    const unsigned short* __restrict__ hm0, const unsigned short* __restrict__ M1,
    const unsigned short* __restrict__ M2v, unsigned short* __restrict__ M2o,
    const unsigned short* __restrict__ tb, const unsigned short* __restrict__ T2v,
    unsigned short* __restrict__ T3o,
    const unsigned short* __restrict__ WB, const float* __restrict__ BB,
    int gm, int gt) {
    __shared__ __align__(16) unsigned short wlds[128 * HDIM];
    const int b = blockIdx.x;
    const int rep = b & 7;
    const unsigned short* WL0 = WB + (size_t)rep * WTOT + 8192;
    const float* BR = BB + rep * BREP;
    if (b < gm) {
        tile_core_lds<HDIM, true, true, true, true, false>(
            wlds, hm0, WL0 + 6 * WHH, M1, WL0 + 0 * WHH, M2v, BR + 384, M2o, NMOV, b);
    } else {
        tile_core_lds<HDIM, true, false, true, true, false>(
            wlds, tb, WL0 + 5 * WHH, T2v, WL0 + 2 * WHH, nullptr, BR + 256, T3o, NTAG, b - gm);
    }
}

// layer-1 update, movie only (user fused; tag dead)
__global__ __launch_bounds__(256, 5) void upd_l1(
    const unsigned short* __restrict__ M2, const unsigned short* __restrict__ M1,
    const unsigned short* __restrict__ M3v, float* __restrict__ out_m,
    const unsigned short* __restrict__ WB, const float* __restrict__ BB) {
    __shared__ __align__(16) unsigned short wlds[128 * HDIM];
    const int b = blockIdx.x;
    const int rep = b & 7;
    const unsigned short* WL1 = WB + (size_t)rep * WTOT + 8192 + 7 * WHH;
    const float* BR = BB + rep * BREP;
    tile_core_lds<HDIM, true, true, true, true, true>(
        wlds, M2, WL1 + 6 * WHH, M1, WL1 + 0 * WHH, M3v, BR + 640, out_m, NMOV, b);
}

// ---------------------------------------------------------------------------
extern "C" void kernel_launch(void* const* d_in, const int* in_sizes, int n_in,
                              void* d_out, int out_size, void* d_ws, size_t ws_size,
                              hipStream_t stream) {
    const float* genre    = (const float*)d_in[0];
    const float* user_emb = (const float*)d_in[1];
    const float* tag_emb  = (const float*)d_in[2];
    const float* movie_W  = (const float*)d_in[3];
    const float* movie_b  = (const float*)d_in[4];
    const float* Wn       = (const float*)d_in[5];
    const float* Wsf      = (const float*)d_in[6];
    const float* bsf      = (const float*)d_in[7];
    const int* rates_u    = (const int*)d_in[8];
    const int* rates_m    = (const int*)d_in[9];
    const int* tag_m      = (const int*)d_in[10];
    const int* tag_t      = (const int*)d_in[11];

    float* out_u = (float*)d_out;                 // NUSR x H (f32)
    float* out_m = out_u + (size_t)NUSR * HDIM;   // NMOV x H (f32)

    // ---- workspace carve-up ----
    char* w = (char*)d_ws;
    auto alloc = [&](size_t bytes) -> char* {
        char* p = w;
        w += (bytes + 511) & ~(size_t)511;
        return p;
    };
    unsigned short* ub  = (unsigned short*)alloc((size_t)NUSR * HDIM * 2);
    unsigned short* tb  = (unsigned short*)alloc((size_t)NTAG * HDIM * 2);
    unsigned short* gb  = (unsigned short*)alloc((size_t)NMOV * FDIM * 2);
    unsigned short* hm0 = (unsigned short*)alloc((size_t)NMOV * HDIM * 2);  // L0 hm; L1: mean(T1) scratch
    unsigned short* U1  = (unsigned short*)alloc((size_t)NUSR * HDIM * 2);
    unsigned short* M1  = (unsigned short*)alloc((size_t)NMOV * HDIM * 2);
    unsigned short* M2  = (unsigned short*)alloc((size_t)NMOV * HDIM * 2);
    unsigned short* M3  = (unsigned short*)alloc((size_t)NMOV * HDIM * 2);
    unsigned short* T1  = (unsigned short*)alloc((size_t)NTAG * HDIM * 2);
    unsigned short* T2  = (unsigned short*)alloc((size_t)NTAG * HDIM * 2);
    unsigned short* T3  = (unsigned short*)alloc((size_t)NTAG * HDIM * 2);
    unsigned short* WB  = (unsigned short*)alloc((size_t)8 * WTOT * 2);     // 8 swizzled replicas
    float* BB           = (float*)alloc((size_t)8 * BREP * 4);
    int* rowptr         = (int*)alloc((size_t)(NTOT + 1) * 4);
    int* sorted         = (int*)alloc((size_t)ETOT * 4);
    int* tmpb           = (int*)alloc((size_t)ETOT * 4);
    int* bcnt           = (int*)alloc((size_t)(NB + 1) * 4);
    int* bbase          = (int*)alloc((size_t)(NB + 1) * 4);
    int* bcur           = (int*)alloc((size_t)(NB + 1) * 4);

    const int GU = cdiv(NUSR, 64), GM = cdiv(NMOV, 64), GT = cdiv(NTAG, 64);

    // 1) conversions + replicated swizzled weight prep + bcnt zero
    const int n0 = NUSR * HDIM / 4, n1 = NTAG * HDIM / 4, n2 = NMOV * FDIM / 4;
    const int GCVT = cdiv(n0 + n1 + n2, 256);
    const int GWT  = cdiv(WTOT, 256);
    prep_all<<<GCVT + GWT, 256, 0, stream>>>(user_emb, ub, n0, tag_emb, tb, n1, genre, gb, n2,
                                             GCVT, movie_W, movie_b, Wn, Wsf, bsf, WB, BB, bcnt);

    // 2) CSR bucket-hist + genre GEMM
    hist_genre<<<S1_NBLK + GM, 256, 0, stream>>>(rates_u, rates_m, tag_m, tag_t, bcnt, S1_NBLK,
                                                 gb, WB, BB, hm0, NMOV);

    // 3) bucket-scan + layer-0 pre-transforms (M3 = hm0@Wn01, T1 = tb@Wn03)
    bscan_pre2<<<1 + GM + GT, 256, 0, stream>>>(bcnt, bbase, bcur, rowptr,
                                                hm0, M3, NMOV, GM, tb, T1, NTAG,
                                                WB, 8192 + 1 * WHH, 8192 + 3 * WHH);

    // 4-5) CSR bin + sort
    csr_bin<<<S1_NBLK, 256, 0, stream>>>(rates_u, rates_m, tag_m, tag_t, bcur, tmpb);
    csr_sort<<<NB, 256, 0, stream>>>(tmpb, bbase, rowptr, sorted);

    // ================= layer 0 =================
    agg4<<<cdiv(2 * NMOV + NTAG, 16), 256, 0, stream>>>(
        ub, rowptr + OFF_RM, M1,          // mean(hu)    -> movies (B operand)
        T1, rowptr + OFF_TM, M2,          // mean(tmp_t) -> movies (addv)
        hm0, rowptr + OFF_TT, T2,         // mean(hm)    -> tags (B operand)
        nullptr, nullptr, nullptr,
        NMOV, 2 * NMOV, 2 * NMOV + NTAG, 2 * NMOV + NTAG, sorted);
    fused_user<false><<<GU, 256, 0, stream>>>(ub, M3, rowptr + OFF_RU, sorted,
                                              WB, 8192 + 4 * WHH, BB, 128, U1, NUSR);
    upd_l0<<<GM + GT, 256, 0, stream>>>(hm0, M1, M2, M2, tb, T2, T3, WB, BB, GM, GT);

    // ================= layer 1 (tag dead; outputs f32 -> d_out) =================
    gemm_pre2<<<GM + GT, 256, 0, stream>>>(M2, M3, NMOV, GM, T3, T1, NTAG,
                                           WB, 8192 + 7 * WHH + 1 * WHH, 8192 + 7 * WHH + 3 * WHH);
    agg4<<<cdiv(2 * NMOV, 16), 256, 0, stream>>>(
        U1, rowptr + OFF_RM, M1,          // mean(hu1)   -> movies (B operand)
        T1, rowptr + OFF_TM, hm0,         // mean(tmp_t) -> movies (addv; hm0 dead)
        nullptr, nullptr, nullptr,
        nullptr, nullptr, nullptr,
        NMOV, 2 * NMOV, 2 * NMOV, 2 * NMOV, sorted);
    fused_user<true><<<GU, 256, 0, stream>>>(U1, M3, rowptr + OFF_RU, sorted,
                                             WB, 8192 + 7 * WHH + 4 * WHH, BB, 512, out_u, NUSR);
    upd_l1<<<GM, 256, 0, stream>>>(M2, M1, hm0, out_m, WB, BB);
}

// Round 16
// 389.951 us; speedup vs baseline: 1.1084x; 1.1084x over previous
//
#include <hip/hip_runtime.h>
#include <stdint.h>

// ---------------------------------------------------------------------------
// HeteroGraphSAGE encoder, MI355X round 16 = round 14 (session best, 390us).
// Round-15 post-mortem: fusing the user mean into the update GEMM regressed
// (88us x2 at 27% occupancy + LDS conflicts vs ~105us combined unfused).
// Standalone agg4 at 72% occupancy is the best gather engine; revert.
// Structure: bf16 everywhere; bucketized coalesced CSR; LDS-staged
// pre-swizzled-W MFMA GEMMs (global_load_lds w16); merged small launches.
// ---------------------------------------------------------------------------

#define NUSR 200000
#define NMOV 50000
#define NTAG 20000
#define FDIM 64
#define HDIM 128
#define NE1  800000
#define NE2  400000

#define OFF_RM 0
#define OFF_RU (NMOV)
#define OFF_TM (NMOV + NUSR)
#define OFF_TT (NMOV + NUSR + NMOV)
#define NTOT   (2 * NMOV + NUSR + NTAG)      // 320000
#define ETOT   (2 * NE1 + 2 * NE2)           // 2.4M
#define WHH    (HDIM * HDIM)

#define WTOT (8192 + 2 * 7 * WHH)
#define BREP 768

#define NB0 196
#define NB1 196
#define NB2 98
#define NB3 157
#define NB  (NB0 + NB1 + NB2 + NB3)          // 647
#define S1_EPB 8192
#define S1_B0 98
#define S1_B1 98
#define S1_B2 49
#define S1_B3 49
#define S1_NBLK (S1_B0 + S1_B1 + S1_B2 + S1_B3)  // 294
#define CAP 6144

typedef short bf16x8 __attribute__((ext_vector_type(8)));
typedef float f32x4 __attribute__((ext_vector_type(4)));

static inline int cdiv(int a, int b) { return (a + b - 1) / b; }

__device__ __forceinline__ float bf2f(unsigned short u) {
    union { unsigned int i; float f; } c;
    c.i = ((unsigned int)u) << 16;
    return c.f;
}
__device__ __forceinline__ unsigned short f2bf(float f) {
    union { float f; unsigned int i; } c;
    c.f = f;
    unsigned int i = c.i;
    return (unsigned short)((i + 0x7fffu + ((i >> 16) & 1u)) >> 16);  // RNE
}

__device__ __forceinline__ void gload_lds16(const unsigned short* g, unsigned short* l) {
    __builtin_amdgcn_global_load_lds(
        (const __attribute__((address_space(1))) unsigned int*)(g),
        (__attribute__((address_space(3))) unsigned int*)(l), 16, 0, 0);
}

// ---------------------------------------------------------------------------
// CSR build pieces (round-4 bucketized design)
// ---------------------------------------------------------------------------
struct SegInfo {
    int e0, eN, sh, sbb, nb;
    const int* dstA;
    const int* srcA;
};
__device__ __forceinline__ SegInfo seg_decode(int blk, const int* ru, const int* rm,
                                              const int* tm, const int* tt) {
    SegInfo s;
    if (blk < S1_B0) {
        s.e0 = blk * S1_EPB; s.eN = NE1; s.sh = 8;  s.sbb = 0;                 s.nb = NB0;
        s.dstA = rm; s.srcA = ru;
    } else if (blk < S1_B0 + S1_B1) {
        s.e0 = (blk - S1_B0) * S1_EPB; s.eN = NE1; s.sh = 10; s.sbb = NB0;     s.nb = NB1;
        s.dstA = ru; s.srcA = rm;
    } else if (blk < S1_B0 + S1_B1 + S1_B2) {
        s.e0 = (blk - S1_B0 - S1_B1) * S1_EPB; s.eN = NE2; s.sh = 9;
        s.sbb = NB0 + NB1; s.nb = NB2;
        s.dstA = tm; s.srcA = tt;
    } else {
        s.e0 = (blk - S1_B0 - S1_B1 - S1_B2) * S1_EPB; s.eN = NE2; s.sh = 7;
        s.sbb = NB0 + NB1 + NB2; s.nb = NB3;
        s.dstA = tt; s.srcA = tm;
    }
    return s;
}

__global__ __launch_bounds__(256) void csr_bin(const int* __restrict__ ru,
                                               const int* __restrict__ rm,
                                               const int* __restrict__ tm,
                                               const int* __restrict__ tt,
                                               int* __restrict__ bcur,
                                               int* __restrict__ tmp) {
    __shared__ int h[256], st[256], gb[256], cu[256];
    __shared__ int rec[S1_EPB];
    __shared__ unsigned short bk[S1_EPB];
    const int t = threadIdx.x;
    h[t] = 0;
    __syncthreads();
    const SegInfo s = seg_decode(blockIdx.x, ru, rm, tm, tt);
    const int mask = (1 << s.sh) - 1;
#pragma unroll 4
    for (int i = 0; i < S1_EPB / 256; ++i) {
        const int e = s.e0 + t + i * 256;
        if (e < s.eN) atomicAdd(&h[s.dstA[e] >> s.sh], 1);
    }
    __syncthreads();
    const int v = h[t];
    cu[t] = v;
    __syncthreads();
    for (int off = 1; off < 256; off <<= 1) {
        const int add = (t >= off) ? cu[t - off] : 0;
        __syncthreads();
        cu[t] += add;
        __syncthreads();
    }
    st[t] = cu[t] - v;
    gb[t] = (t < s.nb && v) ? atomicAdd(&bcur[s.sbb + t], v) : 0;
    cu[t] = st[t];
    __syncthreads();
#pragma unroll 4
    for (int i = 0; i < S1_EPB / 256; ++i) {
        const int e = s.e0 + t + i * 256;
        if (e < s.eN) {
            const int d = s.dstA[e];
            const int lb = d >> s.sh;
            const int r = ((d & mask) << 18) | s.srcA[e];
            const int p = atomicAdd(&cu[lb], 1);
            rec[p] = r;
            bk[p] = (unsigned short)lb;
        }
    }
    __syncthreads();
    const int ecount = min(S1_EPB, s.eN - s.e0);
    for (int q = t; q < ecount; q += 256) {
        const int lb = bk[q];
        tmp[gb[lb] + (q - st[lb])] = rec[q];
    }
}

__global__ __launch_bounds__(256) void csr_sort(const int* __restrict__ tmp,
                                                const int* __restrict__ bbase,
                                                int* __restrict__ rowptr,
                                                int* __restrict__ sorted) {
    __shared__ int h[1024];
    __shared__ int part[256];
    __shared__ int outb[CAP];
    const int b = blockIdx.x;
    const int t = threadIdx.x;
    int c0, nctr;
    if (b < NB0)                 { c0 = OFF_RM + (b << 8);                nctr = min(256,  NMOV - (b << 8)); }
    else if (b < NB0 + NB1)      { const int j = b - NB0;                 c0 = OFF_RU + (j << 10); nctr = min(1024, NUSR - (j << 10)); }
    else if (b < NB0 + NB1 + NB2){ const int j = b - NB0 - NB1;           c0 = OFF_TM + (j << 9);  nctr = min(512,  NMOV - (j << 9)); }
    else                         { const int j = b - NB0 - NB1 - NB2;     c0 = OFF_TT + (j << 7);  nctr = min(128,  NTAG - (j << 7)); }
    for (int k = t; k < 1024; k += 256) h[k] = 0;
    __syncthreads();
    const int lo = bbase[b], hi = bbase[b + 1];
    const int n = hi - lo;
    for (int e = lo + t; e < hi; e += 256) atomicAdd(&h[tmp[e] >> 18], 1);
    __syncthreads();
    const int b4 = t * 4;
    const int a0 = h[b4], a1 = h[b4 + 1], a2 = h[b4 + 2], a3 = h[b4 + 3];
    const int sum = a0 + a1 + a2 + a3;
    part[t] = sum;
    __syncthreads();
    for (int off = 1; off < 256; off <<= 1) {
        const int add = (t >= off) ? part[t - off] : 0;
        __syncthreads();
        part[t] += add;
        __syncthreads();
    }
    int run = part[t] - sum;
    h[b4] = run; run += a0;
    h[b4 + 1] = run; run += a1;
    h[b4 + 2] = run; run += a2;
    h[b4 + 3] = run;
    __syncthreads();
    for (int k = t; k < nctr; k += 256) rowptr[c0 + k] = lo + h[k];
    __syncthreads();
    if (n <= CAP) {
        for (int e = lo + t; e < hi; e += 256) {
            const int r = tmp[e];
            const int p = atomicAdd(&h[r >> 18], 1);
            outb[p] = r & 0x3FFFF;
        }
        __syncthreads();
        for (int q = t; q < n; q += 256) sorted[lo + q] = outb[q];
    } else {
        for (int e = lo + t; e < hi; e += 256) {
            const int r = tmp[e];
            const int p = atomicAdd(&h[r >> 18], 1);
            sorted[lo + p] = r & 0x3FFFF;
        }
    }
}

// ---------------------------------------------------------------------------
// merged prep: f32->bf16 converts + 8-replica SWIZZLED weight pack + biases
// + zero bcnt.
// ---------------------------------------------------------------------------
__global__ __launch_bounds__(256) void prep_all(
    const float* __restrict__ i0, unsigned short* __restrict__ o0, int n0,
    const float* __restrict__ i1, unsigned short* __restrict__ o1, int n1,
    const float* __restrict__ i2, unsigned short* __restrict__ o2, int n2,
    int gcvt,
    const float* __restrict__ movie_W, const float* __restrict__ movie_b,
    const float* __restrict__ Wn, const float* __restrict__ Ws,
    const float* __restrict__ bs,
    unsigned short* __restrict__ WB, float* __restrict__ BB,
    int* __restrict__ bcnt) {
    if ((int)blockIdx.x < gcvt) {
        int i = blockIdx.x * 256 + threadIdx.x;
        const float* in; unsigned short* out;
        if (i < n0) { in = i0; out = o0; }
        else if (i < n0 + n1) { in = i1; out = o1; i -= n0; }
        else if (i < n0 + n1 + n2) { in = i2; out = o2; i -= n0 + n1; }
        else return;
        const float4 v = ((const float4*)in)[i];
        ushort4 o;
        o.x = f2bf(v.x); o.y = f2bf(v.y); o.z = f2bf(v.z); o.w = f2bf(v.w);
        ((ushort4*)out)[i] = o;
        return;
    }
    const int i = (blockIdx.x - gcvt) * 256 + threadIdx.x;
    if (i <= NB) bcnt[i] = 0;
    if (i < BREP) {
        const int seg = i >> 7, c = i & 127;
        float bv;
        if (seg == 0)      bv = movie_b[c];
        else if (seg == 1) bv = bs[0 * 512 + 1 * 128 + c];
        else if (seg == 2) bv = bs[0 * 512 + 2 * 128 + c];
        else if (seg == 3) bv = bs[0 * 512 + 0 * 128 + c] + bs[0 * 512 + 3 * 128 + c];
        else if (seg == 4) bv = bs[1 * 512 + 1 * 128 + c];
        else               bv = bs[1 * 512 + 0 * 128 + c] + bs[1 * 512 + 3 * 128 + c];
#pragma unroll
        for (int r = 0; r < 8; ++r) BB[r * BREP + i] = bv;
    }
    if (i < WTOT) {
        float v;
        int dest;
        if (i < 8192) {
            v = movie_W[i];
            const int r0 = i >> 6, c0 = i & 63;
            dest = (r0 << 6) + ((((c0 >> 3) ^ (r0 & 7)) << 3) | (c0 & 7));
        } else {
            const int j = i - 8192;
            const int l = j / (7 * WHH);
            const int rr = j % (7 * WHH);
            const int e = rr / WHH;
            const int o = rr % WHH;
            if (e < 4) v = Wn[(l * 4 + e) * WHH + o];
            else if (e == 4) v = Ws[(l * 4 + 1) * WHH + o];
            else if (e == 5) v = Ws[(l * 4 + 2) * WHH + o];
            else v = Ws[(l * 4 + 0) * WHH + o] + Ws[(l * 4 + 3) * WHH + o];
            const int r0 = o >> 7, c0 = o & 127;
            dest = 8192 + l * 7 * WHH + e * WHH +
                   (r0 << 7) + ((((c0 >> 3) ^ (r0 & 7)) << 3) | (c0 & 7));
        }
        const unsigned short bf = f2bf(v);
#pragma unroll
        for (int r = 0; r < 8; ++r) WB[(size_t)r * WTOT + dest] = bf;
    }
}

// ---------------------------------------------------------------------------
// merged mean aggregation (round-12 proven): 16-lane groups, 2-deep unroll,
// bf16 in/out, VGPR ~24 -> 8 waves/SIMD.
// ---------------------------------------------------------------------------
__global__ __launch_bounds__(256) void agg4(
    const unsigned short* __restrict__ f0, const int* __restrict__ rp0, unsigned short* __restrict__ o0,
    const unsigned short* __restrict__ f1, const int* __restrict__ rp1, unsigned short* __restrict__ o1,
    const unsigned short* __restrict__ f2, const int* __restrict__ rp2, unsigned short* __restrict__ o2,
    const unsigned short* __restrict__ f3, const int* __restrict__ rp3, unsigned short* __restrict__ o3,
    int c0, int c1, int c2, int c3,
    const int* __restrict__ sorted) {
    int g = blockIdx.x * 16 + (threadIdx.x >> 4);
    const unsigned short* feat; const int* rp; unsigned short* out;
    if (g < c0) { feat = f0; rp = rp0; out = o0; }
    else if (g < c1) { feat = f1; rp = rp1; out = o1; g -= c0; }
    else if (g < c2) { feat = f2; rp = rp2; out = o2; g -= c1; }
    else if (g < c3) { feat = f3; rp = rp3; out = o3; g -= c2; }
    else return;
    const int lane = threadIdx.x & 15;
    const int s = rp[g], e = rp[g + 1];
    float a[8];
#pragma unroll
    for (int k = 0; k < 8; ++k) a[k] = 0.f;
    int j = s;
    for (; j + 1 < e; j += 2) {
        const int s0 = sorted[j], s1 = sorted[j + 1];
        const bf16x8 v0 = *(const bf16x8*)&feat[(size_t)s0 * HDIM + lane * 8];
        const bf16x8 v1 = *(const bf16x8*)&feat[(size_t)s1 * HDIM + lane * 8];
#pragma unroll
        for (int k = 0; k < 8; ++k) a[k] += bf2f((unsigned short)v0[k]) + bf2f((unsigned short)v1[k]);
    }
    if (j < e) {
        const int s0 = sorted[j];
        const bf16x8 v0 = *(const bf16x8*)&feat[(size_t)s0 * HDIM + lane * 8];
#pragma unroll
        for (int k = 0; k < 8; ++k) a[k] += bf2f((unsigned short)v0[k]);
    }
    const float sc = (e > s) ? 1.0f / (float)(e - s) : 0.0f;
    bf16x8 o;
#pragma unroll
    for (int k = 0; k < 8; ++k) o[k] = (short)f2bf(a[k] * sc);
    *(bf16x8*)&out[(size_t)g * HDIM + lane * 8] = o;
}

// ---------------------------------------------------------------------------
// GEMM tile core (round-12, verified): one 64x128 tile per 256-thr block;
// W staged into LDS via global_load_lds (source rows pre-swizzled).
// ---------------------------------------------------------------------------
template <int K, bool TWO, bool HAS_ADD, bool HAS_BIAS, bool LEAKY, bool OUT_F32>
__device__ __forceinline__ void tile_core_lds(
    unsigned short* wlds,
    const unsigned short* __restrict__ X1, const unsigned short* __restrict__ W1s,
    const unsigned short* __restrict__ X2, const unsigned short* __restrict__ W2s,
    const unsigned short* __restrict__ addv, const float* __restrict__ bias,
    void* __restrict__ out, int n, int blk) {
    constexpr int NC = K / 32;
    constexpr int PASSES = (128 * K) / 2048;
    const int t = threadIdx.x;
    const int lane = t & 63;
    const int wv = t >> 6;
    const int fr = lane & 15, fq = lane >> 4;
    const int swz = fr & 7;
    const int r = blk * 64 + wv * 16 + fr;
    const int rc = (r < n) ? r : (n - 1);

#pragma unroll
    for (int p = 0; p < PASSES; ++p)
        gload_lds16(W1s + (p * 256 + t) * 8, wlds + (p * 256 + t) * 8);

    bf16x8 xf[NC];
    {
        const unsigned short* xp = X1 + (size_t)rc * K + fq * 8;
#pragma unroll
        for (int c = 0; c < NC; ++c) xf[c] = *(const bf16x8*)(xp + c * 32);
    }

    f32x4 acc[8];
#pragma unroll
    for (int nn = 0; nn < 8; ++nn) acc[nn] = (f32x4){0.f, 0.f, 0.f, 0.f};

    __syncthreads();

#pragma unroll
    for (int nn = 0; nn < 8; ++nn) {
        const int rowoff = (nn * 16 + fr) * K;
#pragma unroll
        for (int c = 0; c < NC; ++c) {
            const bf16x8 wf = *(const bf16x8*)&wlds[rowoff + (((fq + 4 * c) ^ swz) << 3)];
            acc[nn] = __builtin_amdgcn_mfma_f32_16x16x32_bf16(wf, xf[c], acc[nn], 0, 0, 0);
        }
    }

    if (TWO) {
        __syncthreads();
#pragma unroll
        for (int p = 0; p < PASSES; ++p)
            gload_lds16(W2s + (p * 256 + t) * 8, wlds + (p * 256 + t) * 8);
        {
            const unsigned short* xp = X2 + (size_t)rc * K + fq * 8;
#pragma unroll
            for (int c = 0; c < NC; ++c) xf[c] = *(const bf16x8*)(xp + c * 32);
        }
        __syncthreads();
#pragma unroll
        for (int nn = 0; nn < 8; ++nn) {
            const int rowoff = (nn * 16 + fr) * K;
#pragma unroll
            for (int c = 0; c < NC; ++c) {
                const bf16x8 wf = *(const bf16x8*)&wlds[rowoff + (((fq + 4 * c) ^ swz) << 3)];
                acc[nn] = __builtin_amdgcn_mfma_f32_16x16x32_bf16(wf, xf[c], acc[nn], 0, 0, 0);
            }
        }
    }

    if (r < n) {
#pragma unroll
        for (int nn = 0; nn < 8; ++nn) {
            const int c0 = nn * 16 + fq * 4;
            float v0 = acc[nn][0], v1 = acc[nn][1], v2 = acc[nn][2], v3 = acc[nn][3];
            if (HAS_BIAS) {
                const float4 bv = *(const float4*)&bias[c0];
                v0 += bv.x; v1 += bv.y; v2 += bv.z; v3 += bv.w;
            }
            if (HAS_ADD) {
                const ushort4 ad = *(const ushort4*)&addv[(size_t)r * HDIM + c0];
                v0 += bf2f(ad.x); v1 += bf2f(ad.y); v2 += bf2f(ad.z); v3 += bf2f(ad.w);
            }
            if (LEAKY) {
                v0 = v0 > 0.f ? v0 : 0.1f * v0;
                v1 = v1 > 0.f ? v1 : 0.1f * v1;
                v2 = v2 > 0.f ? v2 : 0.1f * v2;
                v3 = v3 > 0.f ? v3 : 0.1f * v3;
            }
            if (OUT_F32) {
                float4 o; o.x = v0; o.y = v1; o.z = v2; o.w = v3;
                *(float4*)&((float*)out)[(size_t)r * HDIM + c0] = o;
            } else {
                ushort4 o;
                o.x = f2bf(v0); o.y = f2bf(v1); o.z = f2bf(v2); o.w = f2bf(v3);
                *(ushort4*)&((unsigned short*)out)[(size_t)r * HDIM + c0] = o;
            }
        }
    }
}

// ---------------------------------------------------------------------------
// merged: CSR bucket-hist (blocks [0,nhist)) + genre GEMM (rest).
// ---------------------------------------------------------------------------
__global__ __launch_bounds__(256, 5) void hist_genre(
    const int* __restrict__ ru, const int* __restrict__ rm,
    const int* __restrict__ tm, const int* __restrict__ tt,
    int* __restrict__ bcnt, int nhist,
    const unsigned short* __restrict__ X, const unsigned short* __restrict__ WB,
    const float* __restrict__ BB, unsigned short* __restrict__ out, int n) {
    __shared__ __align__(16) unsigned short wlds[128 * FDIM];
    const int b = blockIdx.x;
    if (b < nhist) {
        int* h = (int*)wlds;
        const int t = threadIdx.x;
        h[t] = 0;
        __syncthreads();
        const SegInfo s = seg_decode(b, ru, rm, tm, tt);
#pragma unroll 4
        for (int i = 0; i < S1_EPB / 256; ++i) {
            const int e = s.e0 + t + i * 256;
            if (e < s.eN) atomicAdd(&h[s.dstA[e] >> s.sh], 1);
        }
        __syncthreads();
        if (t < s.nb) {
            const int c = h[t];
            if (c) atomicAdd(&bcnt[s.sbb + t], c);
        }
        return;
    }
    const int gb = b - nhist;
    const int rep = gb & 7;
    tile_core_lds<FDIM, false, false, true, false, false>(
        wlds, X, WB + (size_t)rep * WTOT, nullptr, nullptr, nullptr,
        BB + rep * BREP, out, n, gb);
}

// ---------------------------------------------------------------------------
// merged: bucket-scan (block 0, 256-thr) + layer-0 pre-transform GEMMs.
// ---------------------------------------------------------------------------
__global__ __launch_bounds__(256, 5) void bscan_pre2(
    const int* __restrict__ bcnt, int* __restrict__ bbase, int* __restrict__ bcur,
    int* __restrict__ rowptr,
    const unsigned short* __restrict__ Xa, unsigned short* __restrict__ oa, int na, int nba,
    const unsigned short* __restrict__ Xb, unsigned short* __restrict__ ob, int nb_,
    const unsigned short* __restrict__ WB, int offA, int offB) {
    __shared__ __align__(16) unsigned short wlds[128 * HDIM];
    const int b = blockIdx.x;
    if (b == 0) {
        int* sh = (int*)wlds;
        const int t = threadIdx.x;
        int v[3];
        int s = 0;
#pragma unroll
        for (int k = 0; k < 3; ++k) {
            const int idx = t * 3 + k;
            v[k] = (idx < NB) ? bcnt[idx] : 0;
            s += v[k];
        }
        sh[t] = s;
        __syncthreads();
        for (int off = 1; off < 256; off <<= 1) {
            const int add = (t >= off) ? sh[t - off] : 0;
            __syncthreads();
            sh[t] += add;
            __syncthreads();
        }
        int run = sh[t] - s;
#pragma unroll
        for (int k = 0; k < 3; ++k) {
            const int idx = t * 3 + k;
            if (idx < NB) { bbase[idx] = run; bcur[idx] = run; }
            run += v[k];
        }
        if (t == 255) bbase[NB] = run;
        if (t == 0) rowptr[NTOT] = ETOT;
        return;
    }
    const int pb = b - 1;
    const int rep = pb & 7;
    const unsigned short* WR = WB + (size_t)rep * WTOT;
    if (pb < nba)
        tile_core_lds<HDIM, false, false, false, false, false>(
            wlds, Xa, WR + offA, nullptr, nullptr, nullptr, nullptr, oa, na, pb);
    else
        tile_core_lds<HDIM, false, false, false, false, false>(
            wlds, Xb, WR + offB, nullptr, nullptr, nullptr, nullptr, ob, nb_, pb - nba);
}

// plain pre2 (layer 1)
__global__ __launch_bounds__(256, 5) void gemm_pre2(
    const unsigned short* __restrict__ Xa, unsigned short* __restrict__ oa, int na, int nba,
    const unsigned short* __restrict__ Xb, unsigned short* __restrict__ ob, int nb_,
    const unsigned short* __restrict__ WB, int offA, int offB) {
    __shared__ __align__(16) unsigned short wlds[128 * HDIM];
    const int b = blockIdx.x;
    const int rep = b & 7;
    const unsigned short* WR = WB + (size_t)rep * WTOT;
    if (b < nba)
        tile_core_lds<HDIM, false, false, false, false, false>(
            wlds, Xa, WR + offA, nullptr, nullptr, nullptr, nullptr, oa, na, b);
    else
        tile_core_lds<HDIM, false, false, false, false, false>(
            wlds, Xb, WR + offB, nullptr, nullptr, nullptr, nullptr, ob, nb_, b - nba);
}

// layer-0 update: user + movie + tag (tag writes T3, never in-place)
__global__ __launch_bounds__(256, 5) void upd_l0(
    const unsigned short* __restrict__ ub, const unsigned short* __restrict__ U1v,
    unsigned short* __restrict__ U1o,
    const unsigned short* __restrict__ hm0, const unsigned short* __restrict__ M1,
    const unsigned short* __restrict__ M2v, unsigned short* __restrict__ M2o,
    const unsigned short* __restrict__ tb, const unsigned short* __restrict__ T2v,
    unsigned short* __restrict__ T3o,
    const unsigned short* __restrict__ WB, const float* __restrict__ BB,
    int gu, int gm, int gt) {
    __shared__ __align__(16) unsigned short wlds[128 * HDIM];
    const int b = blockIdx.x;
    const int rep = b & 7;
    const unsigned short* WL0 = WB + (size_t)rep * WTOT + 8192;
    const float* BR = BB + rep * BREP;
    if (b < gu) {
        tile_core_lds<HDIM, false, true, true, true, false>(
            wlds, ub, WL0 + 4 * WHH, nullptr, nullptr, U1v, BR + 128, U1o, NUSR, b);
    } else if (b < gu + gm) {
        tile_core_lds<HDIM, true, true, true, true, false>(
            wlds, hm0, WL0 + 6 * WHH, M1, WL0 + 0 * WHH, M2v, BR + 384, M2o, NMOV, b - gu);
    } else {
        tile_core_lds<HDIM, true, false, true, true, false>(
            wlds, tb, WL0 + 5 * WHH, T2v, WL0 + 2 * WHH, nullptr, BR + 256, T3o, NTAG, b - gu - gm);
    }
}

// layer-1 update: user + movie (f32 out to d_out); tag dead
__global__ __launch_bounds__(256, 5) void upd_l1(
    const unsigned short* __restrict__ U1, const unsigned short* __restrict__ U2v,
    float* __restrict__ out_u,
    const unsigned short* __restrict__ M2, const unsigned short* __restrict__ M1,
    const unsigned short* __restrict__ M3v, float* __restrict__ out_m,
    const unsigned short* __restrict__ WB, const float* __restrict__ BB,
    int gu, int gm) {
    __shared__ __align__(16) unsigned short wlds[128 * HDIM];
    const int b = blockIdx.x;
    const int rep = b & 7;
    const unsigned short* WL1 = WB + (size_t)rep * WTOT + 8192 + 7 * WHH;
    const float* BR = BB + rep * BREP;
    if (b < gu) {
        tile_core_lds<HDIM, false, true, true, true, true>(
            wlds, U1, WL1 + 4 * WHH, nullptr, nullptr, U2v, BR + 512, out_u, NUSR, b);
    } else {
        tile_core_lds<HDIM, true, true, true, true, true>(
            wlds, M2, WL1 + 6 * WHH, M1, WL1 + 0 * WHH, M3v, BR + 640, out_m, NMOV, b - gu);
    }
}

// ---------------------------------------------------------------------------
extern "C" void kernel_launch(void* const* d_in, const int* in_sizes, int n_in,
                              void* d_out, int out_size, void* d_ws, size_t ws_size,
                              hipStream_t stream) {
    const float* genre    = (const float*)d_in[0];
    const float* user_emb = (const float*)d_in[1];
    const float* tag_emb  = (const float*)d_in[2];
    const float* movie_W  = (const float*)d_in[3];
    const float* movie_b  = (const float*)d_in[4];
    const float* Wn       = (const float*)d_in[5];
    const float* Wsf      = (const float*)d_in[6];
    const float* bsf      = (const float*)d_in[7];
    const int* rates_u    = (const int*)d_in[8];
    const int* rates_m    = (const int*)d_in[9];
    const int* tag_m      = (const int*)d_in[10];
    const int* tag_t      = (const int*)d_in[11];

    float* out_u = (float*)d_out;                 // NUSR x H (f32)
    float* out_m = out_u + (size_t)NUSR * HDIM;   // NMOV x H (f32)

    // ---- workspace carve-up ----
    char* w = (char*)d_ws;
    auto alloc = [&](size_t bytes) -> char* {
        char* p = w;
        w += (bytes + 511) & ~(size_t)511;
        return p;
    };
    unsigned short* ub  = (unsigned short*)alloc((size_t)NUSR * HDIM * 2);  // L0 user; L1: U2 agg scratch
    unsigned short* tb  = (unsigned short*)alloc((size_t)NTAG * HDIM * 2);
    unsigned short* gb  = (unsigned short*)alloc((size_t)NMOV * FDIM * 2);
    unsigned short* hm0 = (unsigned short*)alloc((size_t)NMOV * HDIM * 2);  // L0 hm; L1: mean(T1) scratch
    unsigned short* U1  = (unsigned short*)alloc((size_t)NUSR * HDIM * 2);
    unsigned short* M1  = (unsigned short*)alloc((size_t)NMOV * HDIM * 2);
    unsigned short* M2  = (unsigned short*)alloc((size_t)NMOV * HDIM * 2);
    unsigned short* M3  = (unsigned short*)alloc((size_t)NMOV * HDIM * 2);
    unsigned short* T1  = (unsigned short*)alloc((size_t)NTAG * HDIM * 2);
    unsigned short* T2  = (unsigned short*)alloc((size_t)NTAG * HDIM * 2);
    unsigned short* T3  = (unsigned short*)alloc((size_t)NTAG * HDIM * 2);
    unsigned short* WB  = (unsigned short*)alloc((size_t)8 * WTOT * 2);     // 8 swizzled replicas
    float* BB           = (float*)alloc((size_t)8 * BREP * 4);
    int* rowptr         = (int*)alloc((size_t)(NTOT + 1) * 4);
    int* sorted         = (int*)alloc((size_t)ETOT * 4);
    int* tmpb           = (int*)alloc((size_t)ETOT * 4);
    int* bcnt           = (int*)alloc((size_t)(NB + 1) * 4);
    int* bbase          = (int*)alloc((size_t)(NB + 1) * 4);
    int* bcur           = (int*)alloc((size_t)(NB + 1) * 4);

    const int GU = cdiv(NUSR, 64), GM = cdiv(NMOV, 64), GT = cdiv(NTAG, 64);

    // 1) conversions + replicated swizzled weight prep + bcnt zero
    const int n0 = NUSR * HDIM / 4, n1 = NTAG * HDIM / 4, n2 = NMOV * FDIM / 4;
    const int GCVT = cdiv(n0 + n1 + n2, 256);
    const int GWT  = cdiv(WTOT, 256);
    prep_all<<<GCVT + GWT, 256, 0, stream>>>(user_emb, ub, n0, tag_emb, tb, n1, genre, gb, n2,
                                             GCVT, movie_W, movie_b, Wn, Wsf, bsf, WB, BB, bcnt);

    // 2) CSR bucket-hist + genre GEMM (hm0 = genre @ movie_W.T + movie_b)
    hist_genre<<<S1_NBLK + GM, 256, 0, stream>>>(rates_u, rates_m, tag_m, tag_t, bcnt, S1_NBLK,
                                                 gb, WB, BB, hm0, NMOV);

    // 3) bucket-scan + layer-0 pre-transforms
    bscan_pre2<<<1 + GM + GT, 256, 0, stream>>>(bcnt, bbase, bcur, rowptr,
                                                hm0, M3, NMOV, GM, tb, T1, NTAG,
                                                WB, 8192 + 1 * WHH, 8192 + 3 * WHH);

    // 4-5) CSR bin + sort
    csr_bin<<<S1_NBLK, 256, 0, stream>>>(rates_u, rates_m, tag_m, tag_t, bcur, tmpb);
    csr_sort<<<NB, 256, 0, stream>>>(tmpb, bbase, rowptr, sorted);

    // ================= layer 0 =================
    agg4<<<cdiv(NTOT, 16), 256, 0, stream>>>(
        M3, rowptr + OFF_RU, U1,          // mean(tmp_m) -> users (addv)
        ub, rowptr + OFF_RM, M1,          // mean(hu)    -> movies (B operand)
        T1, rowptr + OFF_TM, M2,          // mean(tmp_t) -> movies (addv)
        hm0, rowptr + OFF_TT, T2,         // mean(hm)    -> tags (B operand)
        NUSR, NUSR + NMOV, NUSR + 2 * NMOV, NTOT, sorted);
    upd_l0<<<GU + GM + GT, 256, 0, stream>>>(ub, U1, U1, hm0, M1, M2, M2,
                                             tb, T2, T3, WB, BB, GU, GM, GT);

    // ================= layer 1 (tag update dead; outputs f32 -> d_out) =========
    gemm_pre2<<<GM + GT, 256, 0, stream>>>(M2, M3, NMOV, GM, T3, T1, NTAG,
                                           WB, 8192 + 7 * WHH + 1 * WHH, 8192 + 7 * WHH + 3 * WHH);
    agg4<<<cdiv(NUSR + 2 * NMOV, 16), 256, 0, stream>>>(
        M3, rowptr + OFF_RU, ub,          // mean(tmp_m) -> users (addv; ub dead)
        U1, rowptr + OFF_RM, M1,          // mean(hu1)   -> movies (B operand)
        T1, rowptr + OFF_TM, hm0,         // mean(tmp_t) -> movies (addv; hm0 dead)
        nullptr, nullptr, nullptr,
        NUSR, NUSR + NMOV, NUSR + 2 * NMOV, NUSR + 2 * NMOV, sorted);
    upd_l1<<<GU + GM, 256, 0, stream>>>(U1, ub, out_u, M2, M1, hm0, out_m,
                                        WB, BB, GU, GM);
}